// Round 15
// baseline (652.793 us; speedup 1.0000x reference)
//
#include <hip/hip_runtime.h>

#define NU 100000
#define NI 50000
#define DD 64
#define ALPHA_C 1.0f
#define EPS_CLAMP 1e-6f

typedef _Float16 h4 __attribute__((ext_vector_type(4)));

__device__ __forceinline__ float rsum16(float v) {
  v += __shfl_xor(v, 1, 64);
  v += __shfl_xor(v, 2, 64);
  v += __shfl_xor(v, 4, 64);
  v += __shfl_xor(v, 8, 64);
  return v;
}
__device__ __forceinline__ float xgrp2(float v) {
  v += __shfl_xor(v, 16, 64);
  v += __shfl_xor(v, 32, 64);
  return v;
}
__device__ __forceinline__ float wsum(float v) { return xgrp2(rsum16(v)); }

// --- K1: fused {norms + item sums + fp16 tables | degree counts + ranks} -------
#define GN_NORM 1024
__global__ void k_norm_count(const float* __restrict__ x, float* __restrict__ inv_norm,
                             float* __restrict__ nrm, h4* __restrict__ xnih,
                             h4* __restrict__ vuh,
                             float* __restrict__ sum_xi, float* __restrict__ sum_vi,
                             const int* __restrict__ u, const int* __restrict__ it,
                             int* __restrict__ du, int* __restrict__ di,
                             unsigned short* __restrict__ ru_, unsigned short* __restrict__ ri_,
                             int E) {
  if ((int)blockIdx.x >= GN_NORM) {
    int bloc = (int)blockIdx.x - GN_NORM;
    int nb = (int)gridDim.x - GN_NORM;
    int t = bloc * blockDim.x + threadIdx.x;
    int stride = nb * blockDim.x;
    for (int e = t; e < E; e += stride) {
      int uu = __builtin_nontemporal_load(&u[e]);
      int ii = __builtin_nontemporal_load(&it[e]);
      ru_[e] = (unsigned short)atomicAdd(&du[uu], 1);
      ri_[e] = (unsigned short)atomicAdd(&di[ii], 1);
    }
    return;
  }
  __shared__ float sx_s[DD], sv_s[DD];
  if (threadIdx.x < DD) { sx_s[threadIdx.x] = 0.f; sv_s[threadIdx.x] = 0.f; }
  __syncthreads();
  int lane = threadIdx.x & 63;
  int g = lane >> 4, c = lane & 15;
  int wid = blockIdx.x * 4 + (threadIdx.x >> 6);
  int nw  = GN_NORM * 4;
  float sx0=0,sx1=0,sx2=0,sx3=0, sv0=0,sv1=0,sv2=0,sv3=0;
  for (int rb = wid * 4; rb < NU + NI; rb += nw * 4) {
    int r = rb + g;
    const float4 v4 = *(const float4*)(x + (size_t)r * DD + 4 * c);
    float p = v4.x*v4.x + v4.y*v4.y + v4.z*v4.z + v4.w*v4.w;
    p = rsum16(p);
    float nc  = fmaxf(sqrtf(p), 1e-12f);
    float inv = 1.0f / nc;
    if (c == 0) inv_norm[r] = inv;
    if (r >= NU) {
      int j = r - NU;
      if (c == 0) nrm[j] = nc;
      float xn0 = v4.x*inv, xn1 = v4.y*inv, xn2 = v4.z*inv, xn3 = v4.w*inv;
      h4 hw = { (_Float16)xn0, (_Float16)xn1, (_Float16)xn2, (_Float16)xn3 };
      xnih[(size_t)j * 16 + c] = hw;
      sv0 += v4.x; sv1 += v4.y; sv2 += v4.z; sv3 += v4.w;
      sx0 += xn0;  sx1 += xn1;  sx2 += xn2;  sx3 += xn3;
    } else {
      h4 hw = { (_Float16)v4.x, (_Float16)v4.y, (_Float16)v4.z, (_Float16)v4.w };
      vuh[(size_t)r * 16 + c] = hw;
    }
  }
  atomicAdd(&sx_s[4*c+0], sx0); atomicAdd(&sx_s[4*c+1], sx1);
  atomicAdd(&sx_s[4*c+2], sx2); atomicAdd(&sx_s[4*c+3], sx3);
  atomicAdd(&sv_s[4*c+0], sv0); atomicAdd(&sv_s[4*c+1], sv1);
  atomicAdd(&sv_s[4*c+2], sv2); atomicAdd(&sv_s[4*c+3], sv3);
  __syncthreads();
  if (threadIdx.x < DD) {
    atomicAdd(&sum_xi[threadIdx.x], sx_s[threadIdx.x]);
    atomicAdd(&sum_vi[threadIdx.x], sv_s[threadIdx.x]);
  }
}

// --- K3: two single-block exclusive scans --------------------------------------
__global__ void k_scan2(const int* __restrict__ cnt0, int n0, int* __restrict__ off0,
                        const int* __restrict__ cnt1, int n1, int* __restrict__ off1) {
  const int* cnt = blockIdx.x ? cnt1 : cnt0;
  int n          = blockIdx.x ? n1   : n0;
  int* off       = blockIdx.x ? off1 : off0;
  __shared__ int wsum_s[16];
  __shared__ int carry_s;
  int t = threadIdx.x, lane = t & 63, wv = t >> 6;
  if (t == 0) carry_s = 0;
  __syncthreads();
  for (int base = 0; base < n; base += 1024 * 8) {
    int v[8];
    int s = 0;
    int i0 = base + t * 8;
#pragma unroll
    for (int k = 0; k < 8; ++k) {
      int idx = i0 + k;
      v[k] = (idx < n) ? cnt[idx] : 0;
      s += v[k];
    }
    int incl = s;
#pragma unroll
    for (int d = 1; d < 64; d <<= 1) {
      int t2 = __shfl_up(incl, d, 64);
      if (lane >= d) incl += t2;
    }
    if (lane == 63) wsum_s[wv] = incl;
    __syncthreads();
    int woff = 0, total = 0;
#pragma unroll
    for (int w = 0; w < 16; ++w) {
      int ws_v = wsum_s[w];
      woff += (w < wv) ? ws_v : 0;
      total += ws_v;
    }
    int excl = carry_s + woff + incl - s;
#pragma unroll
    for (int k = 0; k < 8; ++k) {
      int idx = i0 + k;
      if (idx < n) off[idx] = excl;
      excl += v[k];
    }
    __syncthreads();
    if (t == 0) carry_s += total;
    __syncthreads();
  }
  if (t == 0) off[n] = carry_s;
}

// --- K4: fused {outer products | atomic-free scatter} ---------------------------
#define GRID_OUT 256
#define GS_OUT 85
#define OCH 32
__global__ void k_fused_os(const float* __restrict__ x, const float* __restrict__ inv_norm,
                           const int* __restrict__ du, float* __restrict__ part,
                           const int* __restrict__ u, const int* __restrict__ it,
                           const unsigned short* __restrict__ ru_,
                           const unsigned short* __restrict__ ri_,
                           const int* __restrict__ uoff, const int* __restrict__ ioff, int E,
                           unsigned short* __restrict__ uev,
                           unsigned long long* __restrict__ iue) {
  __shared__ float rows_s[OCH * DD];
  __shared__ float w_s[OCH];
  if ((int)blockIdx.x >= GRID_OUT) {
    int bloc = (int)blockIdx.x - GRID_OUT;
    int nb = (int)gridDim.x - GRID_OUT;
    int t = bloc * blockDim.x + threadIdx.x;
    int stride = nb * blockDim.x;
    for (int e = t; e < E; e += stride) {
      int uu = __builtin_nontemporal_load(&u[e]);
      int ii = __builtin_nontemporal_load(&it[e]);
      int pu = uoff[uu] + (int)__builtin_nontemporal_load(&ru_[e]);
      int pi = ioff[ii] + (int)__builtin_nontemporal_load(&ri_[e]);
      uev[pu] = (unsigned short)ii;
      iue[pi] = (unsigned long long)(unsigned)uu |
                ((unsigned long long)(unsigned)pu << 32);
    }
    return;
  }
  bool isT = (int)blockIdx.x >= GS_OUT;
  int bloc = isT ? (int)blockIdx.x - GS_OUT : (int)blockIdx.x;
  int nb   = isT ? (GRID_OUT - GS_OUT) : GS_OUT;
  int nrows = isT ? NU : NI;
  int row0  = isT ? 0 : NU;
  int t = threadIdx.x;
  int a0 = (t >> 4) << 2;
  int b0 = (t & 15) << 2;
  float acc[4][4];
#pragma unroll
  for (int i = 0; i < 4; ++i)
#pragma unroll
    for (int j = 0; j < 4; ++j) acc[i][j] = 0.f;
  int nch = (nrows + OCH - 1) / OCH;
  int limit = row0 + nrows;
  for (int ch = bloc; ch < nch; ch += nb) {
    int rbase = row0 + ch * OCH;
    __syncthreads();
    {
      const float4* src = (const float4*)(x + (size_t)rbase * DD);
      float4* dst = (float4*)rows_s;
      int r1 = rbase + (t >> 4);
      dst[t] = (r1 < limit) ? src[t] : make_float4(0.f, 0.f, 0.f, 0.f);
      int r2 = rbase + ((t + 256) >> 4);
      dst[t + 256] = (r2 < limit) ? src[t + 256] : make_float4(0.f, 0.f, 0.f, 0.f);
      if (t < OCH) {
        int r = rbase + t;
        float w = 0.f;
        if (r < limit) {
          w = inv_norm[r];
          if (isT) w /= fmaxf((float)NI - (float)du[r], 1.0f);
        }
        w_s[t] = w;
      }
    }
    __syncthreads();
#pragma unroll 8
    for (int r = 0; r < OCH; ++r) {
      float w = w_s[r];
      const float4 av = *(const float4*)(rows_s + r * DD + a0);
      const float4 bv = *(const float4*)(rows_s + r * DD + b0);
      float wa0 = av.x * w, wa1 = av.y * w, wa2 = av.z * w, wa3 = av.w * w;
      acc[0][0] += wa0 * bv.x; acc[0][1] += wa0 * bv.y; acc[0][2] += wa0 * bv.z; acc[0][3] += wa0 * bv.w;
      acc[1][0] += wa1 * bv.x; acc[1][1] += wa1 * bv.y; acc[1][2] += wa1 * bv.z; acc[1][3] += wa1 * bv.w;
      acc[2][0] += wa2 * bv.x; acc[2][1] += wa2 * bv.y; acc[2][2] += wa2 * bv.z; acc[2][3] += wa2 * bv.w;
      acc[3][0] += wa3 * bv.x; acc[3][1] += wa3 * bv.y; acc[3][2] += wa3 * bv.z; acc[3][3] += wa3 * bv.w;
    }
  }
  float* dst = part + (size_t)blockIdx.x * (DD * DD);
#pragma unroll
  for (int i = 0; i < 4; ++i)
    *(float4*)(dst + (size_t)(a0 + i) * DD + b0) =
        make_float4(acc[i][0], acc[i][1], acc[i][2], acc[i][3]);
}

// --- K6b: reduce partials into Smat/Tmat ------------------------------------------
__global__ void k_redST(const float* __restrict__ part,
                        float* __restrict__ Smat, float* __restrict__ Tmat) {
  int k = blockIdx.x * blockDim.x + threadIdx.x;
  if (k < DD * DD) {
    float s = 0.f;
    for (int b = 0; b < GS_OUT; ++b) s += part[(size_t)b * (DD * DD) + k];
    Smat[k] = s;
  } else {
    int kk = k - DD * DD;
    float s = 0.f;
    for (int b = GS_OUT; b < GRID_OUT; ++b) s += part[(size_t)b * (DD * DD) + kk];
    Tmat[kk] = s;
  }
}

// --- K6c: xs/xt matvec -> out ------------------------------------------------------
__global__ void k_matvec(const float* __restrict__ x, const float* __restrict__ inv_norm,
                         const float* __restrict__ Smat, const float* __restrict__ Tmat,
                         float* __restrict__ out, int gU) {
  bool isI = (int)blockIdx.x >= gU;
  const float* M = isI ? Tmat : Smat;
  int row0  = isI ? NU : 0;
  int nrows = isI ? NI : NU;
  int bloc  = isI ? (int)blockIdx.x - gU : (int)blockIdx.x;
  int nb    = isI ? (int)gridDim.x - gU : gU;
  int lane = threadIdx.x & 63;
  float m_reg[DD];
#pragma unroll
  for (int a = 0; a < DD; ++a) m_reg[a] = M[a * DD + lane];
  int wid = bloc * (blockDim.x >> 6) + (threadIdx.x >> 6);
  int nw  = nb * (blockDim.x >> 6);
  for (int rr = wid; rr < nrows; rr += nw) {
    int r = row0 + rr;
    float v = x[(size_t)r * DD + lane] * inv_norm[r];
    float a0 = 0.f, a1 = 0.f, a2 = 0.f, a3 = 0.f;
#pragma unroll
    for (int a = 0; a < DD; a += 4) {
      a0 += __shfl(v, a)     * m_reg[a];
      a1 += __shfl(v, a + 1) * m_reg[a + 1];
      a2 += __shfl(v, a + 2) * m_reg[a + 2];
      a3 += __shfl(v, a + 3) * m_reg[a + 3];
    }
    out[(size_t)r * DD + lane] = (a0 + a1) + (a2 + a3);
  }
}

// --- K7: per-user pass — fp16 gathers, te written linearly in user-CSR order --------
__global__ void k_user8(const float* __restrict__ x, const float* __restrict__ inv_norm,
                        const float* __restrict__ nrm, const h4* __restrict__ xnih,
                        const int* __restrict__ uoff, const unsigned short* __restrict__ uev,
                        const float* __restrict__ sum_xi, const float* __restrict__ sum_vi,
                        float2* __restrict__ te, float* __restrict__ out,
                        float* __restrict__ Gx, float* __restrict__ Gv, float* __restrict__ Gb) {
  __shared__ float gx_s[DD], gv_s[DD], gb_s;
  if (threadIdx.x < DD) { gx_s[threadIdx.x] = 0.f; gv_s[threadIdx.x] = 0.f; }
  if (threadIdx.x == 0) gb_s = 0.f;
  __syncthreads();
  int lane = threadIdx.x & 63;
  int g = lane >> 4, c = lane & 15;
  float gmask = (g == 0) ? 1.f : 0.f;
  int wid = blockIdx.x * (blockDim.x >> 6) + (threadIdx.x >> 6);
  int nw  = gridDim.x * (blockDim.x >> 6);
  const float4 sx4  = *(const float4*)(sum_xi + 4 * c);
  const float4 svl4 = *(const float4*)(sum_vi + 4 * c);
  float* tex2 = (float*)te;
  float gxa0=0,gxa1=0,gxa2=0,gxa3=0, gva0=0,gva1=0,gva2=0,gva3=0, gb=0.f;
  for (int uu = wid; uu < NU; uu += nw) {
    size_t ru = (size_t)uu * DD;
    int beg = uoff[uu], end2 = uoff[uu + 1];
    int deg = end2 - beg;
    float a1 = 1.0f / fmaxf((float)deg, 1.0f);
    float a2 = 1.0f / fmaxf((float)(NI - deg), 1.0f);
    float invu = inv_norm[uu];
    const float4 v4 = *(const float4*)(x + ru + 4 * c);
    float4 xu4 = make_float4(v4.x*invu, v4.y*invu, v4.z*invu, v4.w*invu);
    float Av0=0,Av1=0,Av2=0,Av3=0, sv0=0,sv1=0,sv2=0,sv3=0;
    float sA = 0.f, dmine = 0.f;
    bool multi = deg > 64;
    for (int base = beg; base < end2; base += 64) {
      int nb2 = end2 - base; if (nb2 > 64) nb2 = 64;
      int ii_l = 0; float nc_l = 0.f;
      if (lane < nb2) {
        ii_l = (int)uev[base + lane];
        nc_l = nrm[ii_l];
      }
      dmine = 0.f;
      for (int k0 = 0; k0 < nb2; k0 += 4) {
        int   ii = __shfl(ii_l, k0 + g);
        float nc = __shfl(nc_l, k0 + g);
        float f  = (k0 + g < nb2) ? 1.f : 0.f;
        h4 hv = xnih[(size_t)ii * 16 + c];
        float r0 = (float)hv.x, r1 = (float)hv.y, r2 = (float)hv.z, r3 = (float)hv.w;
        float p = xu4.x*r0 + xu4.y*r1 + xu4.z*r2 + xu4.w*r3;
        float d = f * rsum16(p);
        float w = d * nc;
        Av0 += w * r0; Av1 += w * r1; Av2 += w * r2; Av3 += w * r3;
        sv0 += nc * r0; sv1 += nc * r1; sv2 += nc * r2; sv3 += nc * r3;
        sA += d;
        float cand = __shfl(d, (lane & 3) << 4);
        if ((lane & 60) == k0) dmine = cand;
      }
      if (multi && lane < nb2) tex2[2 * (size_t)(base + lane)] = dmine;
    }
    sA  = xgrp2(sA);
    Av0 = xgrp2(Av0); Av1 = xgrp2(Av1); Av2 = xgrp2(Av2); Av3 = xgrp2(Av3);
    sv0 = xgrp2(sv0); sv1 = xgrp2(sv1); sv2 = xgrp2(sv2); sv3 = xgrp2(sv3);
    float bp = sA * a1;
    float pbn = xu4.x*sx4.x + xu4.y*sx4.y + xu4.z*sx4.z + xu4.w*sx4.w;
    float bn = (rsum16(pbn) - sA) * a2;
    float s1 = (ALPHA_C - bn) * a1;
    float s2 = (bp + ALPHA_C) * a2;
    if (!multi) {
      if (lane < deg) te[beg + lane] = make_float2(dmine * a1 + s1, dmine * a2 - s2);
    } else {
      for (int k = beg + lane; k < end2; k += 64) {
        float dv = tex2[2 * (size_t)k];
        te[k] = make_float2(dv * a1 + s1, dv * a2 - s2);
      }
    }
    const float4 xs4 = *(const float4*)(out + ru + 4 * c);
    float c12 = s1 + s2, a12 = a1 - a2;
    float rden = 1.0f / (2.0f * fmaxf(bp - bn + ALPHA_C, EPS_CLAMP));
    float o0 = (Av0 * a12 + sv0 * c12 + xs4.x * a2 - svl4.x * s2) * rden;
    float o1 = (Av1 * a12 + sv1 * c12 + xs4.y * a2 - svl4.y * s2) * rden;
    float o2 = (Av2 * a12 + sv2 * c12 + xs4.z * a2 - svl4.z * s2) * rden;
    float o3 = (Av3 * a12 + sv3 * c12 + xs4.w * a2 - svl4.w * s2) * rden;
    if (g == 0) *(float4*)(out + ru + 4 * c) = make_float4(o0, o1, o2, o3);
    float t2m = a2 * gmask, t3m = s2 * gmask;
    gxa0 += t2m * xu4.x; gxa1 += t2m * xu4.y; gxa2 += t2m * xu4.z; gxa3 += t2m * xu4.w;
    gva0 += t3m * v4.x;  gva1 += t3m * v4.y;  gva2 += t3m * v4.z;  gva3 += t3m * v4.w;
    if (lane == 0) gb += s2;
  }
  if (g == 0) {
    atomicAdd(&gx_s[4*c+0], gxa0); atomicAdd(&gx_s[4*c+1], gxa1);
    atomicAdd(&gx_s[4*c+2], gxa2); atomicAdd(&gx_s[4*c+3], gxa3);
    atomicAdd(&gv_s[4*c+0], gva0); atomicAdd(&gv_s[4*c+1], gva1);
    atomicAdd(&gv_s[4*c+2], gva2); atomicAdd(&gv_s[4*c+3], gva3);
  }
  if (lane == 0) atomicAdd(&gb_s, gb);
  __syncthreads();
  if (threadIdx.x < DD) {
    atomicAdd(&Gx[threadIdx.x], gx_s[threadIdx.x]);
    atomicAdd(&Gv[threadIdx.x], gv_s[threadIdx.x]);
  }
  if (threadIdx.x == 0) atomicAdd(Gb, gb_s);
}

// --- K8: per-item pass — te[pu] gather (8B) + vuh gather ------------------------------
__global__ void k_item8(const float* __restrict__ x, const float* __restrict__ inv_norm,
                        const h4* __restrict__ vuh,
                        const int* __restrict__ ioff,
                        const unsigned long long* __restrict__ iue,
                        const float2* __restrict__ te,
                        const float* __restrict__ Gx, const float* __restrict__ Gv,
                        const float* __restrict__ Gb, float* __restrict__ out) {
  int lane = threadIdx.x & 63;
  int g = lane >> 4, c = lane & 15;
  int wid = blockIdx.x * (blockDim.x >> 6) + (threadIdx.x >> 6);
  int nw  = gridDim.x * (blockDim.x >> 6);
  const float4 Gx4 = *(const float4*)(Gx + 4 * c);
  const float4 Gv4 = *(const float4*)(Gv + 4 * c);
  float gbv = *Gb;
  for (int j = wid; j < NI; j += nw) {
    int r = NU + j;
    size_t rr = (size_t)r * DD;
    float invi = inv_norm[r];
    const float4 vi4 = *(const float4*)(x + rr + 4 * c);
    float4 xi4 = make_float4(vi4.x*invi, vi4.y*invi, vi4.z*invi, vi4.w*invi);
    int beg = ioff[j], end2 = ioff[j + 1];
    float W0=0,W1=0,W2=0,W3=0, q1=0.f, q2=0.f;
    for (int base = beg; base < end2; base += 64) {
      int nb2 = end2 - base; if (nb2 > 64) nb2 = 64;
      int uu_l = 0; float glx = 0.f;
      if (lane < nb2) {
        unsigned long long m = iue[base + lane];
        uu_l = (int)(unsigned)m;
        int pu = (int)(m >> 32);
        float2 t = te[pu];
        q1 += t.x; q2 += t.y;
        glx = t.x - t.y;
      }
      for (int k0 = 0; k0 < nb2; k0 += 4) {
        int   ua = __shfl(uu_l, k0 + g);
        float ge = __shfl(glx,  k0 + g);
        h4 hv = vuh[(size_t)ua * 16 + c];
        W0 += ge * (float)hv.x; W1 += ge * (float)hv.y;
        W2 += ge * (float)hv.z; W3 += ge * (float)hv.w;
      }
    }
    q1 = wsum(q1); q2 = wsum(q2);
    W0 = xgrp2(W0); W1 = xgrp2(W1); W2 = xgrp2(W2); W3 = xgrp2(W3);
    float pd = xi4.x*Gx4.x + xi4.y*Gx4.y + xi4.z*Gx4.z + xi4.w*Gx4.w;
    float di1 = q1;
    float di2 = -rsum16(pd) + q2 + gbv;
    const float4 xt4 = *(const float4*)(out + rr + 4 * c);
    float rden = 1.0f / (fmaxf(di1, EPS_CLAMP) + fmaxf(di2, EPS_CLAMP));
    float o0 = (W0 + xt4.x - Gv4.x) * rden;
    float o1 = (W1 + xt4.y - Gv4.y) * rden;
    float o2 = (W2 + xt4.z - Gv4.z) * rden;
    float o3 = (W3 + xt4.w - Gv4.w) * rden;
    if (g == 0) *(float4*)(out + rr + 4 * c) = make_float4(o0, o1, o2, o3);
  }
}

extern "C" void kernel_launch(void* const* d_in, const int* in_sizes, int n_in,
                              void* d_out, int out_size, void* d_ws, size_t ws_size,
                              hipStream_t stream) {
  const float* x  = (const float*)d_in[0];
  const int*   u  = (const int*)d_in[1];
  const int*   it = (const int*)d_in[2];
  float* out = (float*)d_out;
  const int E = in_sizes[1];

  char* wsb = (char*)d_ws;
  size_t off = 0;
  auto alloc = [&](size_t elems) { void* p = wsb + off; off += elems * 4; return p; };

  // zero-init region (contiguous, first)
  int*   du     = (int*)alloc(100016);
  int*   di     = (int*)alloc(50016);
  float* sum_xi = (float*)alloc(64);
  float* sum_vi = (float*)alloc(64);
  float* Gx     = (float*)alloc(64);
  float* Gv     = (float*)alloc(64);
  float* Gb     = (float*)alloc(16);
  size_t zero_bytes = off;

  float* Smat   = (float*)alloc(4096);
  float* Tmat   = (float*)alloc(4096);
  float* part   = (float*)alloc((size_t)GRID_OUT * 4096);
  float*  inv_norm = (float*)alloc(150016);
  float*  nrm      = (float*)alloc(50016);
  h4*     xnih     = (h4*)alloc((size_t)NI * 32);
  h4*     vuh      = (h4*)alloc((size_t)NU * 32);
  int*    uoff     = (int*)alloc(100016);
  int*    ioff     = (int*)alloc(50016);
  unsigned short* ru_ = (unsigned short*)alloc(500000);
  unsigned short* ri_ = (unsigned short*)alloc(500000);
  unsigned short* uev = (unsigned short*)alloc(500000);
  unsigned long long* iue = (unsigned long long*)alloc(2000000);
  float2* te       = (float2*)alloc(2000000);

  hipMemsetAsync(d_ws, 0, zero_bytes, stream);

  k_norm_count<<<GN_NORM + 1024, 256, 0, stream>>>(x, inv_norm, nrm, xnih, vuh,
                                                   sum_xi, sum_vi,
                                                   u, it, du, di, ru_, ri_, E);
  k_scan2<<<2, 1024, 0, stream>>>(du, NU, uoff, di, NI, ioff);
  k_fused_os<<<GRID_OUT + 4096, 256, 0, stream>>>(x, inv_norm, du, part,
                                                  u, it, ru_, ri_, uoff, ioff, E,
                                                  uev, iue);
  k_redST<<<32, 256, 0, stream>>>(part, Smat, Tmat);
  k_matvec<<<1536, 256, 0, stream>>>(x, inv_norm, Smat, Tmat, out, 1024);
  k_user8<<<4096, 256, 0, stream>>>(x, inv_norm, nrm, xnih, uoff, uev, sum_xi, sum_vi,
                                    te, out, Gx, Gv, Gb);
  k_item8<<<4096, 256, 0, stream>>>(x, inv_norm, vuh, ioff, iue, te,
                                    Gx, Gv, Gb, out);
}

// Round 16
// 577.783 us; speedup vs baseline: 1.1298x; 1.1298x over previous
//
#include <hip/hip_runtime.h>

#define NU 100000
#define NI 50000
#define DD 64
#define ALPHA_C 1.0f
#define EPS_CLAMP 1e-6f

typedef _Float16 h4 __attribute__((ext_vector_type(4)));

__device__ __forceinline__ float rsum16(float v) {
  v += __shfl_xor(v, 1, 64);
  v += __shfl_xor(v, 2, 64);
  v += __shfl_xor(v, 4, 64);
  v += __shfl_xor(v, 8, 64);
  return v;
}
__device__ __forceinline__ float xgrp2(float v) {
  v += __shfl_xor(v, 16, 64);
  v += __shfl_xor(v, 32, 64);
  return v;
}
__device__ __forceinline__ float wsum(float v) { return xgrp2(rsum16(v)); }

// --- K1: fused {norms + item sums + fp16 tables | degree counts + ranks} -------
#define GN_NORM 1024
__global__ void k_norm_count(const float* __restrict__ x, float* __restrict__ inv_norm,
                             float* __restrict__ nrm, h4* __restrict__ xnih,
                             h4* __restrict__ vuh,
                             float* __restrict__ sum_xi, float* __restrict__ sum_vi,
                             const int* __restrict__ u, const int* __restrict__ it,
                             int* __restrict__ du, int* __restrict__ di,
                             unsigned short* __restrict__ ru_, unsigned short* __restrict__ ri_,
                             int E) {
  if ((int)blockIdx.x >= GN_NORM) {
    int bloc = (int)blockIdx.x - GN_NORM;
    int nb = (int)gridDim.x - GN_NORM;
    int t = bloc * blockDim.x + threadIdx.x;
    int stride = nb * blockDim.x;
    for (int e = t; e < E; e += stride) {
      int uu = __builtin_nontemporal_load(&u[e]);
      int ii = __builtin_nontemporal_load(&it[e]);
      ru_[e] = (unsigned short)atomicAdd(&du[uu], 1);
      ri_[e] = (unsigned short)atomicAdd(&di[ii], 1);
    }
    return;
  }
  __shared__ float sx_s[DD], sv_s[DD];
  if (threadIdx.x < DD) { sx_s[threadIdx.x] = 0.f; sv_s[threadIdx.x] = 0.f; }
  __syncthreads();
  int lane = threadIdx.x & 63;
  int g = lane >> 4, c = lane & 15;
  int wid = blockIdx.x * 4 + (threadIdx.x >> 6);
  int nw  = GN_NORM * 4;
  float sx0=0,sx1=0,sx2=0,sx3=0, sv0=0,sv1=0,sv2=0,sv3=0;
  for (int rb = wid * 4; rb < NU + NI; rb += nw * 4) {
    int r = rb + g;
    const float4 v4 = *(const float4*)(x + (size_t)r * DD + 4 * c);
    float p = v4.x*v4.x + v4.y*v4.y + v4.z*v4.z + v4.w*v4.w;
    p = rsum16(p);
    float nc  = fmaxf(sqrtf(p), 1e-12f);
    float inv = 1.0f / nc;
    if (c == 0) inv_norm[r] = inv;
    if (r >= NU) {
      int j = r - NU;
      if (c == 0) nrm[j] = nc;
      float xn0 = v4.x*inv, xn1 = v4.y*inv, xn2 = v4.z*inv, xn3 = v4.w*inv;
      h4 hw = { (_Float16)xn0, (_Float16)xn1, (_Float16)xn2, (_Float16)xn3 };
      xnih[(size_t)j * 16 + c] = hw;
      sv0 += v4.x; sv1 += v4.y; sv2 += v4.z; sv3 += v4.w;
      sx0 += xn0;  sx1 += xn1;  sx2 += xn2;  sx3 += xn3;
    } else {
      h4 hw = { (_Float16)v4.x, (_Float16)v4.y, (_Float16)v4.z, (_Float16)v4.w };
      vuh[(size_t)r * 16 + c] = hw;
    }
  }
  atomicAdd(&sx_s[4*c+0], sx0); atomicAdd(&sx_s[4*c+1], sx1);
  atomicAdd(&sx_s[4*c+2], sx2); atomicAdd(&sx_s[4*c+3], sx3);
  atomicAdd(&sv_s[4*c+0], sv0); atomicAdd(&sv_s[4*c+1], sv1);
  atomicAdd(&sv_s[4*c+2], sv2); atomicAdd(&sv_s[4*c+3], sv3);
  __syncthreads();
  if (threadIdx.x < DD) {
    atomicAdd(&sum_xi[threadIdx.x], sx_s[threadIdx.x]);
    atomicAdd(&sum_vi[threadIdx.x], sv_s[threadIdx.x]);
  }
}

// --- K3: two single-block exclusive scans --------------------------------------
__global__ void k_scan2(const int* __restrict__ cnt0, int n0, int* __restrict__ off0,
                        const int* __restrict__ cnt1, int n1, int* __restrict__ off1) {
  const int* cnt = blockIdx.x ? cnt1 : cnt0;
  int n          = blockIdx.x ? n1   : n0;
  int* off       = blockIdx.x ? off1 : off0;
  __shared__ int wsum_s[16];
  __shared__ int carry_s;
  int t = threadIdx.x, lane = t & 63, wv = t >> 6;
  if (t == 0) carry_s = 0;
  __syncthreads();
  for (int base = 0; base < n; base += 1024 * 8) {
    int v[8];
    int s = 0;
    int i0 = base + t * 8;
#pragma unroll
    for (int k = 0; k < 8; ++k) {
      int idx = i0 + k;
      v[k] = (idx < n) ? cnt[idx] : 0;
      s += v[k];
    }
    int incl = s;
#pragma unroll
    for (int d = 1; d < 64; d <<= 1) {
      int t2 = __shfl_up(incl, d, 64);
      if (lane >= d) incl += t2;
    }
    if (lane == 63) wsum_s[wv] = incl;
    __syncthreads();
    int woff = 0, total = 0;
#pragma unroll
    for (int w = 0; w < 16; ++w) {
      int ws_v = wsum_s[w];
      woff += (w < wv) ? ws_v : 0;
      total += ws_v;
    }
    int excl = carry_s + woff + incl - s;
#pragma unroll
    for (int k = 0; k < 8; ++k) {
      int idx = i0 + k;
      if (idx < n) off[idx] = excl;
      excl += v[k];
    }
    __syncthreads();
    if (t == 0) carry_s += total;
    __syncthreads();
  }
  if (t == 0) off[n] = carry_s;
}

// --- K4: fused {outer products | atomic-free scatter} ---------------------------
#define GRID_OUT 256
#define GS_OUT 85
#define OCH 32
__global__ void k_fused_os(const float* __restrict__ x, const float* __restrict__ inv_norm,
                           const int* __restrict__ du, float* __restrict__ part,
                           const int* __restrict__ u, const int* __restrict__ it,
                           const unsigned short* __restrict__ ru_,
                           const unsigned short* __restrict__ ri_,
                           const int* __restrict__ uoff, const int* __restrict__ ioff, int E,
                           int* __restrict__ uev, unsigned long long* __restrict__ iue) {
  __shared__ float rows_s[OCH * DD];
  __shared__ float w_s[OCH];
  if ((int)blockIdx.x >= GRID_OUT) {
    int bloc = (int)blockIdx.x - GRID_OUT;
    int nb = (int)gridDim.x - GRID_OUT;
    int t = bloc * blockDim.x + threadIdx.x;
    int stride = nb * blockDim.x;
    for (int e = t; e < E; e += stride) {
      int uu = __builtin_nontemporal_load(&u[e]);
      int ii = __builtin_nontemporal_load(&it[e]);
      int pu = uoff[uu] + (int)__builtin_nontemporal_load(&ru_[e]);
      int pi = ioff[ii] + (int)__builtin_nontemporal_load(&ri_[e]);
      uev[pu] = ii;
      iue[pi] = (unsigned long long)(unsigned)uu |
                ((unsigned long long)(unsigned)pu << 32);
    }
    return;
  }
  bool isT = (int)blockIdx.x >= GS_OUT;
  int bloc = isT ? (int)blockIdx.x - GS_OUT : (int)blockIdx.x;
  int nb   = isT ? (GRID_OUT - GS_OUT) : GS_OUT;
  int nrows = isT ? NU : NI;
  int row0  = isT ? 0 : NU;
  int t = threadIdx.x;
  int a0 = (t >> 4) << 2;
  int b0 = (t & 15) << 2;
  float acc[4][4];
#pragma unroll
  for (int i = 0; i < 4; ++i)
#pragma unroll
    for (int j = 0; j < 4; ++j) acc[i][j] = 0.f;
  int nch = (nrows + OCH - 1) / OCH;
  int limit = row0 + nrows;
  for (int ch = bloc; ch < nch; ch += nb) {
    int rbase = row0 + ch * OCH;
    __syncthreads();
    {
      const float4* src = (const float4*)(x + (size_t)rbase * DD);
      float4* dst = (float4*)rows_s;
      int r1 = rbase + (t >> 4);
      dst[t] = (r1 < limit) ? src[t] : make_float4(0.f, 0.f, 0.f, 0.f);
      int r2 = rbase + ((t + 256) >> 4);
      dst[t + 256] = (r2 < limit) ? src[t + 256] : make_float4(0.f, 0.f, 0.f, 0.f);
      if (t < OCH) {
        int r = rbase + t;
        float w = 0.f;
        if (r < limit) {
          w = inv_norm[r];
          if (isT) w /= fmaxf((float)NI - (float)du[r], 1.0f);
        }
        w_s[t] = w;
      }
    }
    __syncthreads();
#pragma unroll 8
    for (int r = 0; r < OCH; ++r) {
      float w = w_s[r];
      const float4 av = *(const float4*)(rows_s + r * DD + a0);
      const float4 bv = *(const float4*)(rows_s + r * DD + b0);
      float wa0 = av.x * w, wa1 = av.y * w, wa2 = av.z * w, wa3 = av.w * w;
      acc[0][0] += wa0 * bv.x; acc[0][1] += wa0 * bv.y; acc[0][2] += wa0 * bv.z; acc[0][3] += wa0 * bv.w;
      acc[1][0] += wa1 * bv.x; acc[1][1] += wa1 * bv.y; acc[1][2] += wa1 * bv.z; acc[1][3] += wa1 * bv.w;
      acc[2][0] += wa2 * bv.x; acc[2][1] += wa2 * bv.y; acc[2][2] += wa2 * bv.z; acc[2][3] += wa2 * bv.w;
      acc[3][0] += wa3 * bv.x; acc[3][1] += wa3 * bv.y; acc[3][2] += wa3 * bv.z; acc[3][3] += wa3 * bv.w;
    }
  }
  float* dst = part + (size_t)blockIdx.x * (DD * DD);
#pragma unroll
  for (int i = 0; i < 4; ++i)
    *(float4*)(dst + (size_t)(a0 + i) * DD + b0) =
        make_float4(acc[i][0], acc[i][1], acc[i][2], acc[i][3]);
}

// --- K6b: reduce partials into Smat/Tmat ------------------------------------------
__global__ void k_redST(const float* __restrict__ part,
                        float* __restrict__ Smat, float* __restrict__ Tmat) {
  int k = blockIdx.x * blockDim.x + threadIdx.x;
  if (k < DD * DD) {
    float s = 0.f;
    for (int b = 0; b < GS_OUT; ++b) s += part[(size_t)b * (DD * DD) + k];
    Smat[k] = s;
  } else {
    int kk = k - DD * DD;
    float s = 0.f;
    for (int b = GS_OUT; b < GRID_OUT; ++b) s += part[(size_t)b * (DD * DD) + kk];
    Tmat[kk] = s;
  }
}

// --- K6c: xs/xt matvec -> out ------------------------------------------------------
__global__ void k_matvec(const float* __restrict__ x, const float* __restrict__ inv_norm,
                         const float* __restrict__ Smat, const float* __restrict__ Tmat,
                         float* __restrict__ out, int gU) {
  bool isI = (int)blockIdx.x >= gU;
  const float* M = isI ? Tmat : Smat;
  int row0  = isI ? NU : 0;
  int nrows = isI ? NI : NU;
  int bloc  = isI ? (int)blockIdx.x - gU : (int)blockIdx.x;
  int nb    = isI ? (int)gridDim.x - gU : gU;
  int lane = threadIdx.x & 63;
  float m_reg[DD];
#pragma unroll
  for (int a = 0; a < DD; ++a) m_reg[a] = M[a * DD + lane];
  int wid = bloc * (blockDim.x >> 6) + (threadIdx.x >> 6);
  int nw  = nb * (blockDim.x >> 6);
  for (int rr = wid; rr < nrows; rr += nw) {
    int r = row0 + rr;
    float v = x[(size_t)r * DD + lane] * inv_norm[r];
    float a0 = 0.f, a1 = 0.f, a2 = 0.f, a3 = 0.f;
#pragma unroll
    for (int a = 0; a < DD; a += 4) {
      a0 += __shfl(v, a)     * m_reg[a];
      a1 += __shfl(v, a + 1) * m_reg[a + 1];
      a2 += __shfl(v, a + 2) * m_reg[a + 2];
      a3 += __shfl(v, a + 3) * m_reg[a + 3];
    }
    out[(size_t)r * DD + lane] = (a0 + a1) + (a2 + a3);
  }
}

// --- K7: per-user pass — fp16 item gathers, linear d_raw (round-11 user5 form) ------
__global__ void k_user5(const float* __restrict__ x, const float* __restrict__ inv_norm,
                        const float* __restrict__ nrm, const h4* __restrict__ xnih,
                        const int* __restrict__ uoff, const int* __restrict__ uev,
                        const float* __restrict__ sum_xi, const float* __restrict__ sum_vi,
                        float* __restrict__ d_raw, float4* __restrict__ usc,
                        float* __restrict__ out,
                        float* __restrict__ Gx, float* __restrict__ Gv, float* __restrict__ Gb) {
  __shared__ float gx_s[DD], gv_s[DD], gb_s;
  if (threadIdx.x < DD) { gx_s[threadIdx.x] = 0.f; gv_s[threadIdx.x] = 0.f; }
  if (threadIdx.x == 0) gb_s = 0.f;
  __syncthreads();
  int lane = threadIdx.x & 63;
  int g = lane >> 4, c = lane & 15;
  float gmask = (g == 0) ? 1.f : 0.f;
  int wid = blockIdx.x * (blockDim.x >> 6) + (threadIdx.x >> 6);
  int nw  = gridDim.x * (blockDim.x >> 6);
  const float4 sx4  = *(const float4*)(sum_xi + 4 * c);
  const float4 svl4 = *(const float4*)(sum_vi + 4 * c);
  float gxa0=0,gxa1=0,gxa2=0,gxa3=0, gva0=0,gva1=0,gva2=0,gva3=0, gb=0.f;
  for (int uu = wid; uu < NU; uu += nw) {
    size_t ru = (size_t)uu * DD;
    int beg = uoff[uu], end2 = uoff[uu + 1];
    int deg = end2 - beg;
    float a1 = 1.0f / fmaxf((float)deg, 1.0f);
    float a2 = 1.0f / fmaxf((float)(NI - deg), 1.0f);
    float invu = inv_norm[uu];
    const float4 v4 = *(const float4*)(x + ru + 4 * c);
    float4 xu4 = make_float4(v4.x*invu, v4.y*invu, v4.z*invu, v4.w*invu);
    float Av0=0,Av1=0,Av2=0,Av3=0, sv0=0,sv1=0,sv2=0,sv3=0;
    float sA = 0.f;
    for (int base = beg; base < end2; base += 64) {
      int nb2 = end2 - base; if (nb2 > 64) nb2 = 64;
      int ii_l = 0; float nc_l = 0.f;
      if (lane < nb2) {
        ii_l = uev[base + lane];
        nc_l = nrm[ii_l];
      }
      for (int k0 = 0; k0 < nb2; k0 += 4) {
        int   ii = __shfl(ii_l, k0 + g);
        float nc = __shfl(nc_l, k0 + g);
        float f  = (k0 + g < nb2) ? 1.f : 0.f;
        h4 hv = xnih[(size_t)ii * 16 + c];
        float r0 = (float)hv.x, r1 = (float)hv.y, r2 = (float)hv.z, r3 = (float)hv.w;
        float p = xu4.x*r0 + xu4.y*r1 + xu4.z*r2 + xu4.w*r3;
        float d = f * rsum16(p);
        float w = d * nc;
        Av0 += w * r0; Av1 += w * r1; Av2 += w * r2; Av3 += w * r3;
        sv0 += nc * r0; sv1 += nc * r1; sv2 += nc * r2; sv3 += nc * r3;
        sA += d;
        if (c == 0 && k0 + g < nb2) d_raw[base + k0 + g] = d;
      }
    }
    sA  = xgrp2(sA);
    Av0 = xgrp2(Av0); Av1 = xgrp2(Av1); Av2 = xgrp2(Av2); Av3 = xgrp2(Av3);
    sv0 = xgrp2(sv0); sv1 = xgrp2(sv1); sv2 = xgrp2(sv2); sv3 = xgrp2(sv3);
    float bp = sA * a1;
    float pbn = xu4.x*sx4.x + xu4.y*sx4.y + xu4.z*sx4.z + xu4.w*sx4.w;
    float bn = (rsum16(pbn) - sA) * a2;
    float s1 = (ALPHA_C - bn) * a1;
    float s2 = (bp + ALPHA_C) * a2;
    if (lane == 0) usc[uu] = make_float4(a1, a2, s1, s2);
    const float4 xs4 = *(const float4*)(out + ru + 4 * c);
    float c12 = s1 + s2, a12 = a1 - a2;
    float rden = 1.0f / (2.0f * fmaxf(bp - bn + ALPHA_C, EPS_CLAMP));
    float o0 = (Av0 * a12 + sv0 * c12 + xs4.x * a2 - svl4.x * s2) * rden;
    float o1 = (Av1 * a12 + sv1 * c12 + xs4.y * a2 - svl4.y * s2) * rden;
    float o2 = (Av2 * a12 + sv2 * c12 + xs4.z * a2 - svl4.z * s2) * rden;
    float o3 = (Av3 * a12 + sv3 * c12 + xs4.w * a2 - svl4.w * s2) * rden;
    if (g == 0) *(float4*)(out + ru + 4 * c) = make_float4(o0, o1, o2, o3);
    float t2 = a2 * gmask, t3 = s2 * gmask;
    gxa0 += t2 * xu4.x; gxa1 += t2 * xu4.y; gxa2 += t2 * xu4.z; gxa3 += t2 * xu4.w;
    gva0 += t3 * v4.x;  gva1 += t3 * v4.y;  gva2 += t3 * v4.z;  gva3 += t3 * v4.w;
    if (lane == 0) gb += s2;
  }
  if (g == 0) {
    atomicAdd(&gx_s[4*c+0], gxa0); atomicAdd(&gx_s[4*c+1], gxa1);
    atomicAdd(&gx_s[4*c+2], gxa2); atomicAdd(&gx_s[4*c+3], gxa3);
    atomicAdd(&gv_s[4*c+0], gva0); atomicAdd(&gv_s[4*c+1], gva1);
    atomicAdd(&gv_s[4*c+2], gva2); atomicAdd(&gv_s[4*c+3], gva3);
  }
  if (lane == 0) atomicAdd(&gb_s, gb);
  __syncthreads();
  if (threadIdx.x < DD) {
    atomicAdd(&Gx[threadIdx.x], gx_s[threadIdx.x]);
    atomicAdd(&Gv[threadIdx.x], gv_s[threadIdx.x]);
  }
  if (threadIdx.x == 0) atomicAdd(Gb, gb_s);
}

// --- K8: per-item pass — fp16 user gathers (round-11 item5 form) ---------------------
__global__ void k_item5(const float* __restrict__ x, const float* __restrict__ inv_norm,
                        const h4* __restrict__ vuh,
                        const int* __restrict__ ioff, const uint2* __restrict__ iue,
                        const float* __restrict__ d_raw, const float4* __restrict__ usc,
                        const float* __restrict__ Gx, const float* __restrict__ Gv,
                        const float* __restrict__ Gb, float* __restrict__ out) {
  int lane = threadIdx.x & 63;
  int g = lane >> 4, c = lane & 15;
  int wid = blockIdx.x * (blockDim.x >> 6) + (threadIdx.x >> 6);
  int nw  = gridDim.x * (blockDim.x >> 6);
  const float4 Gx4 = *(const float4*)(Gx + 4 * c);
  const float4 Gv4 = *(const float4*)(Gv + 4 * c);
  float gb = *Gb;
  for (int j = wid; j < NI; j += nw) {
    int r = NU + j;
    size_t rr = (size_t)r * DD;
    float invi = inv_norm[r];
    const float4 vi4 = *(const float4*)(x + rr + 4 * c);
    float4 xi4 = make_float4(vi4.x*invi, vi4.y*invi, vi4.z*invi, vi4.w*invi);
    int beg = ioff[j], end2 = ioff[j + 1];
    float W0=0,W1=0,W2=0,W3=0, q1=0.f, q2=0.f;
    for (int base = beg; base < end2; base += 64) {
      int nb2 = end2 - base; if (nb2 > 64) nb2 = 64;
      int uu_l = 0; float glx = 0.f;
      if (lane < nb2) {
        uint2 m = iue[base + lane];
        uu_l = (int)m.x;
        float d = d_raw[m.y];
        float4 cc = usc[uu_l];
        float t1 = d * cc.x + cc.z;
        float t2 = d * cc.y - cc.w;
        q1 += t1; q2 += t2;
        glx = t1 - t2;
      }
      for (int k0 = 0; k0 < nb2; k0 += 4) {
        int   ua = __shfl(uu_l, k0 + g);
        float ge = __shfl(glx,  k0 + g);
        h4 hv = vuh[(size_t)ua * 16 + c];
        W0 += ge * (float)hv.x; W1 += ge * (float)hv.y;
        W2 += ge * (float)hv.z; W3 += ge * (float)hv.w;
      }
    }
    q1 = wsum(q1); q2 = wsum(q2);
    W0 = xgrp2(W0); W1 = xgrp2(W1); W2 = xgrp2(W2); W3 = xgrp2(W3);
    float pd = xi4.x*Gx4.x + xi4.y*Gx4.y + xi4.z*Gx4.z + xi4.w*Gx4.w;
    float di1 = q1;
    float di2 = -rsum16(pd) + q2 + gb;
    const float4 xt4 = *(const float4*)(out + rr + 4 * c);
    float rden = 1.0f / (fmaxf(di1, EPS_CLAMP) + fmaxf(di2, EPS_CLAMP));
    float o0 = (W0 + xt4.x - Gv4.x) * rden;
    float o1 = (W1 + xt4.y - Gv4.y) * rden;
    float o2 = (W2 + xt4.z - Gv4.z) * rden;
    float o3 = (W3 + xt4.w - Gv4.w) * rden;
    if (g == 0) *(float4*)(out + rr + 4 * c) = make_float4(o0, o1, o2, o3);
  }
}

extern "C" void kernel_launch(void* const* d_in, const int* in_sizes, int n_in,
                              void* d_out, int out_size, void* d_ws, size_t ws_size,
                              hipStream_t stream) {
  const float* x  = (const float*)d_in[0];
  const int*   u  = (const int*)d_in[1];
  const int*   it = (const int*)d_in[2];
  float* out = (float*)d_out;
  const int E = in_sizes[1];

  char* wsb = (char*)d_ws;
  size_t off = 0;
  auto alloc = [&](size_t elems) { void* p = wsb + off; off += elems * 4; return p; };

  // zero-init region (contiguous, first)
  int*   du     = (int*)alloc(100016);
  int*   di     = (int*)alloc(50016);
  float* sum_xi = (float*)alloc(64);
  float* sum_vi = (float*)alloc(64);
  float* Gx     = (float*)alloc(64);
  float* Gv     = (float*)alloc(64);
  float* Gb     = (float*)alloc(16);
  size_t zero_bytes = off;

  float* Smat   = (float*)alloc(4096);
  float* Tmat   = (float*)alloc(4096);
  float* part   = (float*)alloc((size_t)GRID_OUT * 4096);
  float*  inv_norm = (float*)alloc(150016);
  float*  nrm      = (float*)alloc(50016);
  h4*     xnih     = (h4*)alloc((size_t)NI * 32);
  h4*     vuh      = (h4*)alloc((size_t)NU * 32);
  int*    uoff     = (int*)alloc(100016);
  int*    ioff     = (int*)alloc(50016);
  unsigned short* ru_ = (unsigned short*)alloc(500000);
  unsigned short* ri_ = (unsigned short*)alloc(500000);
  int*    uev      = (int*)alloc(1000000);
  unsigned long long* iue = (unsigned long long*)alloc(2000000);
  float*  d_raw    = (float*)alloc(1000000);
  float4* usc      = (float4*)alloc(400000);

  hipMemsetAsync(d_ws, 0, zero_bytes, stream);

  k_norm_count<<<GN_NORM + 1024, 256, 0, stream>>>(x, inv_norm, nrm, xnih, vuh,
                                                   sum_xi, sum_vi,
                                                   u, it, du, di, ru_, ri_, E);
  k_scan2<<<2, 1024, 0, stream>>>(du, NU, uoff, di, NI, ioff);
  k_fused_os<<<GRID_OUT + 4096, 256, 0, stream>>>(x, inv_norm, du, part,
                                                  u, it, ru_, ri_, uoff, ioff, E,
                                                  uev, iue);
  k_redST<<<32, 256, 0, stream>>>(part, Smat, Tmat);
  k_matvec<<<1536, 256, 0, stream>>>(x, inv_norm, Smat, Tmat, out, 1024);
  k_user5<<<2048, 256, 0, stream>>>(x, inv_norm, nrm, xnih, uoff, uev, sum_xi, sum_vi,
                                    d_raw, usc, out, Gx, Gv, Gb);
  k_item5<<<2048, 256, 0, stream>>>(x, inv_norm, vuh, ioff, (const uint2*)iue, d_raw, usc,
                                    Gx, Gv, Gb, out);
}